// Round 9
// baseline (342.788 us; speedup 1.0000x reference)
//
#include <hip/hip_runtime.h>
#include <math.h>

typedef unsigned short u16;
typedef float f32x4 __attribute__((ext_vector_type(4)));
typedef __bf16 bf16x8 __attribute__((ext_vector_type(8)));

#define B_ 2
#define S_ 2048
#define D_ 768
#define H_ 12
#define DH_ 64

__device__ __forceinline__ u16 f2bf(float x) {
  union { float f; unsigned u; } v; v.f = x;
  unsigned r = v.u + 0x7fffu + ((v.u >> 16) & 1u);
  return (u16)(r >> 16);
}

__device__ __forceinline__ f32x4 zero4() { f32x4 z = {0.f, 0.f, 0.f, 0.f}; return z; }

__device__ __forceinline__ f32x4 mfma16(bf16x8 a, bf16x8 b, f32x4 c) {
  return __builtin_amdgcn_mfma_f32_16x16x32_bf16(a, b, c, 0, 0, 0);
}

__device__ __forceinline__ void gload_lds16(const void* g, void* l) {
  __builtin_amdgcn_global_load_lds((const __attribute__((address_space(1))) void*)g,
                                   (__attribute__((address_space(3))) void*)l, 16, 0, 0);
}

// ---------------- f32 -> bf16 conversion (hidden + 4 weights) ----------------
__global__ void cvt_kernel(const float* __restrict__ hid, const float* __restrict__ qw,
                           const float* __restrict__ kw, const float* __restrict__ vw,
                           const float* __restrict__ ow, u16* __restrict__ Hb,
                           u16* __restrict__ Wb) {
  const int NH = B_ * S_ * D_;      // 3145728
  const int NW = D_ * D_;           // 589824
  const int T4 = (NH + 4 * NW) >> 2;
  int stride = gridDim.x * blockDim.x;
  for (int i = blockIdx.x * blockDim.x + threadIdx.x; i < T4; i += stride) {
    int e = i << 2;
    const float* src; u16* dst;
    if (e < NH) { src = hid + e; dst = Hb + e; }
    else {
      int o = e - NH;
      int m = o / NW, oo = o - m * NW;
      src = (m == 0 ? qw : m == 1 ? kw : m == 2 ? vw : ow) + oo;
      dst = Wb + o;
    }
    f32x4 v = *(const f32x4*)src;
    uint2 o2;
    o2.x = (unsigned)f2bf(v[0]) | ((unsigned)f2bf(v[1]) << 16);
    o2.y = (unsigned)f2bf(v[2]) | ((unsigned)f2bf(v[3]) << 16);
    *(uint2*)dst = o2;
  }
}

// ---------------- GEMM: out = A @ W^T (+bias), m97 structure ----------------
#define BM 128
#define BN 128
#define BK 64

__global__ __launch_bounds__(256) void gemm_kernel(
    const u16* __restrict__ A, const u16* __restrict__ W,
    const float* __restrict__ bq, const float* __restrict__ bk, const float* __restrict__ bv,
    u16* __restrict__ Qb, u16* __restrict__ Kb, u16* __restrict__ Vtmp,
    float* __restrict__ Of, const float* __restrict__ bO, int mode)
{
  __shared__ __align__(16) u16 As[BM * BK];
  __shared__ __align__(16) u16 Bs[BN * BK];
  int t = threadIdx.x;
  int lane = t & 63, w = t >> 6;
  int wr = w >> 1, wc = w & 1;
  int l15 = lane & 15, l4 = lane >> 4;
  int m0 = blockIdx.y * BM, n0 = blockIdx.x * BN;

  f32x4 acc[4][4];
#pragma unroll
  for (int i = 0; i < 4; ++i)
#pragma unroll
    for (int j = 0; j < 4; ++j) acc[i][j] = zero4();

  const int K = D_;
  for (int k0 = 0; k0 < K; k0 += BK) {
    __syncthreads();
#pragma unroll
    for (int p = 0; p < 4; ++p) {
      int seg = p * 4 + w;
      int bd = seg * 64 + lane;
      int row = bd >> 3;
      int slot = (bd & 7) ^ (row & 7);
      gload_lds16(A + (size_t)(m0 + row) * K + k0 + slot * 8, (char*)As + seg * 1024);
      gload_lds16(W + (size_t)(n0 + row) * K + k0 + slot * 8, (char*)Bs + seg * 1024);
    }
    __syncthreads();
#pragma unroll
    for (int kk = 0; kk < 2; ++kk) {
      bf16x8 af[4], bfr[4];
#pragma unroll
      for (int i = 0; i < 4; ++i) {
        int ra = wr * 64 + i * 16 + l15;
        af[i] = *(const bf16x8*)((const char*)As + ra * 128 +
                                 ((kk * 64 + (l4 << 4)) ^ ((ra & 7) << 4)));
        int rb = wc * 64 + i * 16 + l15;
        bfr[i] = *(const bf16x8*)((const char*)Bs + rb * 128 +
                                  ((kk * 64 + (l4 << 4)) ^ ((rb & 7) << 4)));
      }
#pragma unroll
      for (int i = 0; i < 4; ++i)
#pragma unroll
        for (int j = 0; j < 4; ++j)
          acc[i][j] = mfma16(af[i], bfr[j], acc[i][j]);
    }
  }

  if (mode == 0) {
    int mat = n0 / D_;
    int ncol0 = (n0 - mat * D_) + wc * 64;
    const float* bias = (mat == 0) ? bq : (mat == 1 ? bk : bv);
    u16* outp = (mat == 0) ? Qb : (mat == 1 ? Kb : Vtmp);
    float scale = (mat == 0) ? 0.125f : 1.0f;
    int h = ncol0 >> 6;
#pragma unroll
    for (int j = 0; j < 4; ++j) {
      int d = j * 16 + l15;
      float bvv = bias[ncol0 + d];
#pragma unroll
      for (int i = 0; i < 4; ++i) {
#pragma unroll
        for (int r = 0; r < 4; ++r) {
          int m = m0 + wr * 64 + i * 16 + (l4 << 2) + r;
          int bb = m >> 11, ss = m & 2047;
          float val = (acc[i][j][r] + bvv) * scale;
          outp[(((size_t)bb * H_ + h) * S_ + ss) * DH_ + d] = f2bf(val);
        }
      }
    }
  } else {
#pragma unroll
    for (int j = 0; j < 4; ++j) {
      int n = n0 + wc * 64 + j * 16 + l15;
      float bvv = bO[n];
#pragma unroll
      for (int i = 0; i < 4; ++i) {
#pragma unroll
        for (int r = 0; r < 4; ++r) {
          int m = m0 + wr * 64 + i * 16 + (l4 << 2) + r;
          Of[(size_t)m * D_ + n] = acc[i][j][r] + bvv;
        }
      }
    }
  }
}

// ---------------- V transpose: [B,H,S,DH] -> [B,H,DH,S] ----------------
__global__ __launch_bounds__(256) void vtrans_kernel(const u16* __restrict__ V,
                                                     u16* __restrict__ Vt) {
  __shared__ __align__(16) u16 tile[64 * 64];
  int t = threadIdx.x;
  int s0 = blockIdx.x * 64;
  int bh = blockIdx.y;
  const u16* src = V + ((size_t)bh * S_ + s0) * DH_;
#pragma unroll
  for (int p = 0; p < 2; ++p) {
    int bd = t + p * 256;
    int row = bd >> 3, slot = bd & 7;
    uint4 v = *(const uint4*)(src + row * 64 + slot * 8);
    *(uint4*)((char*)tile + row * 128 + ((slot ^ (row & 7)) << 4)) = v;
  }
  __syncthreads();
  int d = t >> 2, sc = (t & 3) * 16;
  u16* dst = Vt + ((size_t)bh * DH_ + d) * S_ + s0 + sc;
  int colB = d * 2;
#pragma unroll
  for (int half = 0; half < 2; ++half) {
    u16 tmp[8] __attribute__((aligned(16)));
#pragma unroll
    for (int j = 0; j < 8; ++j) {
      int s = sc + half * 8 + j;
      tmp[j] = *(const u16*)((const char*)tile + s * 128 +
                             (((colB >> 4) ^ (s & 7)) << 4) + (colB & 15));
    }
    *(uint4*)(dst + half * 8) = *(const uint4*)tmp;
  }
}

// ---------------- flash attention: 8-wave split-KV, reg-staged K/V, 2-deep bias ----
// grid (S/64, H, B), 512 threads = 8 waves; wave (qg=w&3, kg=w>>2) owns 16 q-rows
// x 32 kv-cols. K/V staged global->REG->ds_write (no global_load_lds!), so the
// per-iter __syncthreads drains only lgkmcnt; plain global->VGPR bias loads stay
// in flight across barriers, waited by compiler-counted vmcnt at USE. Bias is
// prefetched 2 tiles deep (sets A/B, raw values; adds deferred to the exp).
// Fixed-reference softmax (scores bounded ~|8|); per-lane partial denominators;
// k-split partials combined once in the epilogue (scratch overlays Ps).
__global__ __launch_bounds__(512, 6) void attn_kernel(
    const u16* __restrict__ Qb, const u16* __restrict__ Kb, const u16* __restrict__ Vt,
    const float* __restrict__ bias, const float* __restrict__ mask, u16* __restrict__ Cb)
{
  __shared__ __align__(16) u16 Ks[2][64 * 64];
  __shared__ __align__(16) u16 Vs[2][64 * 64];
  // union region: iter-phase Ps[4][16][72] u16 (9216 B) / epilogue-phase
  // Osh[4][16][66] f32 (16896 B) + Lsh[4][2][16] f32 (512 B) = 17408 B
  __shared__ __align__(16) char upool[17408];
  u16 (*Ps)[16][72] = (u16 (*)[16][72])upool;
  float (*Osh)[16][66] = (float (*)[16][66])upool;
  float (*Lsh)[2][16] = (float (*)[2][16])(upool + 16896);

  int t = threadIdx.x, lane = t & 63, w = t >> 6;
  int qg = w & 3, kg = w >> 2;
  int q0 = blockIdx.x * 64, h = blockIdx.y, b = blockIdx.z;
  size_t bh = (size_t)b * H_ + h;
  const u16* Qp = Qb + (bh * S_ + q0) * DH_;
  const u16* Kp = Kb + bh * S_ * DH_;
  const u16* Vp = Vt + bh * DH_ * S_;             // [64][2048]
  const float* biasp = bias + ((size_t)h * S_ + q0) * S_;
  const float* maskp = mask + (size_t)b * S_;
  int l15 = lane & 15, l4 = lane >> 4;
  int kc0 = kg * 32;                               // this wave's kv-col base

  // per-thread bias row pointers (4 C-rows), shifted to this wave's kv half
  const float* brp0 = biasp + (size_t)(qg * 16 + (l4 << 2) + 0) * S_ + kc0 + l15;
  const float* brp1 = brp0 + S_;
  const float* brp2 = brp1 + S_;
  const float* brp3 = brp2 + S_;
  const float* mkp = maskp + kc0 + l15;

  // reg-staging addresses: thread handles row srow, 16B slot sslot
  int srow = t >> 3, sslot = t & 7;
  const u16* gK = Kp + (size_t)srow * DH_ + sslot * 8;   // + kt*4096 (u16)
  const u16* gV = Vp + (size_t)srow * S_ + sslot * 8;    // + kt*64   (u16)
  int lofs = srow * 128 + ((sslot ^ (srow & 7)) << 4);   // swizzled LDS byte offset

  // Q fragments (softmax scale pre-folded)
  bf16x8 qf0, qf1;
  {
    const u16* qrow = Qp + (qg * 16 + l15) * DH_;
    qf0 = *(const bf16x8*)(qrow + l4 * 8);
    qf1 = *(const bf16x8*)(qrow + 32 + l4 * 8);
  }

  f32x4 oacc[4];
#pragma unroll
  for (int i = 0; i < 4; ++i) oacc[i] = zero4();
  float lrow[4] = {0.f, 0.f, 0.f, 0.f};   // per-lane partial denominators

  // bias sets (raw values; adds happen at use so vmcnt-wait lands at use)
  float bsA[4][2], mA[2];                 // tiles 0,2,4,...
  float bsB[4][2], mB[2];                 // tiles 1,3,5,...
#define LOADSET(BS, MM, kt) do { int kb = (kt) * 64;                         \
    _Pragma("unroll") for (int kf = 0; kf < 2; ++kf) {                       \
      BS[0][kf] = brp0[kb + kf * 16]; BS[1][kf] = brp1[kb + kf * 16];        \
      BS[2][kf] = brp2[kb + kf * 16]; BS[3][kf] = brp3[kb + kf * 16];        \
      MM[kf] = mkp[kb + kf * 16]; } } while (0)

  uint4 stK, stV;

  // ---- prologue ----
  stK = *(const uint4*)gK;                    // tile 0
  stV = *(const uint4*)gV;
  LOADSET(bsA, mA, 0);
  LOADSET(bsB, mB, 1);
  *(uint4*)((char*)Ks[0] + lofs) = stK;       // tile 0 -> LDS[0]
  *(uint4*)((char*)Vs[0] + lofs) = stV;
  stK = *(const uint4*)(gK + 4096);           // tile 1 -> regs
  stV = *(const uint4*)(gV + 64);
  __syncthreads();

  for (int kt = 0; kt < S_ / 64; ++kt) {
    int cur = kt & 1;
    // ---- write staged tile kt+1 into the free buffer; issue K/V loads kt+2 ----
    if (kt + 1 < S_ / 64) {
      *(uint4*)((char*)Ks[cur ^ 1] + lofs) = stK;
      *(uint4*)((char*)Vs[cur ^ 1] + lofs) = stV;
      if (kt + 2 < S_ / 64) {
        stK = *(const uint4*)(gK + (size_t)(kt + 2) * 4096);
        stV = *(const uint4*)(gV + (size_t)(kt + 2) * 64);
      }
    }

    // ---- compute tile kt ----
    const u16* Kc = Ks[cur];
    const u16* Vc = Vs[cur];

    // S = Q K^T (scale pre-folded into Q)
    f32x4 sf[2];
#pragma unroll
    for (int kf = 0; kf < 2; ++kf) {
      int row = kc0 + kf * 16 + l15;
      bf16x8 kb0 = *(const bf16x8*)((const char*)Kc + row * 128 +
                                    ((l4 << 4) ^ ((row & 7) << 4)));
      bf16x8 kb1 = *(const bf16x8*)((const char*)Kc + row * 128 +
                                    ((64 + (l4 << 4)) ^ ((row & 7) << 4)));
      f32x4 s0 = zero4();
      s0 = mfma16(qf0, kb0, s0);
      s0 = mfma16(qf1, kb1, s0);
      sf[kf] = s0;
    }

    // p = exp(s + bias + mask), consuming set (A even / B odd); per-lane denoms
    if ((kt & 1) == 0) {
#pragma unroll
      for (int kf = 0; kf < 2; ++kf) {
        float p0 = __expf(sf[kf][0] + bsA[0][kf] + mA[kf]);
        float p1 = __expf(sf[kf][1] + bsA[1][kf] + mA[kf]);
        float p2 = __expf(sf[kf][2] + bsA[2][kf] + mA[kf]);
        float p3 = __expf(sf[kf][3] + bsA[3][kf] + mA[kf]);
        sf[kf][0] = p0; sf[kf][1] = p1; sf[kf][2] = p2; sf[kf][3] = p3;
        lrow[0] += p0; lrow[1] += p1; lrow[2] += p2; lrow[3] += p3;
      }
      if (kt + 2 < S_ / 64) LOADSET(bsA, mA, kt + 2);   // reissue 2 ahead
    } else {
#pragma unroll
      for (int kf = 0; kf < 2; ++kf) {
        float p0 = __expf(sf[kf][0] + bsB[0][kf] + mB[kf]);
        float p1 = __expf(sf[kf][1] + bsB[1][kf] + mB[kf]);
        float p2 = __expf(sf[kf][2] + bsB[2][kf] + mB[kf]);
        float p3 = __expf(sf[kf][3] + bsB[3][kf] + mB[kf]);
        sf[kf][0] = p0; sf[kf][1] = p1; sf[kf][2] = p2; sf[kf][3] = p3;
        lrow[0] += p0; lrow[1] += p1; lrow[2] += p2; lrow[3] += p3;
      }
      if (kt + 2 < S_ / 64) LOADSET(bsB, mB, kt + 2);
    }

    // P -> bf16, wave-private repack (own 16x32 block only)
#pragma unroll
    for (int r = 0; r < 4; ++r)
#pragma unroll
      for (int kf = 0; kf < 2; ++kf)
        Ps[qg][(l4 << 2) + r][kc0 + kf * 16 + l15] = f2bf(sf[kf][r]);

    bf16x8 pa = *(const bf16x8*)&Ps[qg][l15][kc0 + l4 * 8];

    // O_partial += P V over this wave's k-half
#pragma unroll
    for (int df = 0; df < 4; ++df) {
      int row = df * 16 + l15;
      bf16x8 vb = *(const bf16x8*)((const char*)Vc + row * 128 +
                                   ((kg * 64 + (l4 << 4)) ^ ((row & 7) << 4)));
      oacc[df] = mfma16(pa, vb, oacc[df]);
    }

    // ---- single barrier: orders this iter's LDS reads before next overwrite;
    // drains only lgkm (ds_writes) -- bias/KV register loads stay in flight ----
    __syncthreads();
  }
#undef LOADSET

  // ---- epilogue: combine k-split partials, normalize, write bf16 ----
#pragma unroll
  for (int r = 0; r < 4; ++r) {
#pragma unroll
    for (int o = 1; o < 16; o <<= 1) lrow[r] += __shfl_xor(lrow[r], o, 64);
  }
  if (l15 == 0) {
#pragma unroll
    for (int r = 0; r < 4; ++r) Lsh[qg][kg][(l4 << 2) + r] = lrow[r];
  }
  if (kg == 1) {
#pragma unroll
    for (int r = 0; r < 4; ++r)
#pragma unroll
      for (int df = 0; df < 4; ++df)
        Osh[qg][(l4 << 2) + r][df * 16 + l15] = oacc[df][r];
  }
  __syncthreads();
  if (kg == 0) {
#pragma unroll
    for (int r = 0; r < 4; ++r) {
      int rr = (l4 << 2) + r;
      float inv = 1.0f / (Lsh[qg][0][rr] + Lsh[qg][1][rr]);
      int q = q0 + qg * 16 + rr;
      size_t base = ((size_t)b * S_ + q) * D_ + h * DH_ + l15;
#pragma unroll
      for (int df = 0; df < 4; ++df)
        Cb[base + df * 16] = f2bf((oacc[df][r] + Osh[qg][rr][df * 16 + l15]) * inv);
    }
  }
}

// ---------------- residual + LayerNorm ----------------
__global__ __launch_bounds__(192) void ln_kernel(const float* __restrict__ O,
                                                 const float* __restrict__ hid,
                                                 const float* __restrict__ lw,
                                                 const float* __restrict__ lb,
                                                 float* __restrict__ out) {
  int row = blockIdx.x, t = threadIdx.x;
  size_t base = (size_t)row * D_;
  f32x4 x = *(const f32x4*)(O + base + t * 4);
  f32x4 hh = *(const f32x4*)(hid + base + t * 4);
  x = x + hh;
  float s = x[0] + x[1] + x[2] + x[3];
  float s2 = x[0] * x[0] + x[1] * x[1] + x[2] * x[2] + x[3] * x[3];
#pragma unroll
  for (int o = 1; o < 64; o <<= 1) {
    s += __shfl_xor(s, o, 64);
    s2 += __shfl_xor(s2, o, 64);
  }
  __shared__ float rs[3], rs2[3];
  int w = t >> 6, lane = t & 63;
  if (lane == 0) { rs[w] = s; rs2[w] = s2; }
  __syncthreads();
  s = rs[0] + rs[1] + rs[2];
  s2 = rs2[0] + rs2[1] + rs2[2];
  float mu = s * (1.0f / 768.0f);
  float var = s2 * (1.0f / 768.0f) - mu * mu;
  float rstd = rsqrtf(var + 1e-12f);
  f32x4 w4 = *(const f32x4*)(lw + t * 4);
  f32x4 b4 = *(const f32x4*)(lb + t * 4);
  f32x4 y = (x - mu) * rstd * w4 + b4;
  *(f32x4*)(out + base + t * 4) = y;
}

// ---------------- launcher ----------------
extern "C" void kernel_launch(void* const* d_in, const int* in_sizes, int n_in,
                              void* d_out, int out_size, void* d_ws, size_t ws_size,
                              hipStream_t stream) {
  const float* hid  = (const float*)d_in[0];
  const float* mask = (const float*)d_in[1];
  const float* bias = (const float*)d_in[2];
  const float* qw = (const float*)d_in[3];
  const float* qb = (const float*)d_in[4];
  const float* kw = (const float*)d_in[5];
  const float* kb = (const float*)d_in[6];
  const float* vw = (const float*)d_in[7];
  const float* vb = (const float*)d_in[8];
  const float* ow = (const float*)d_in[9];
  const float* ob = (const float*)d_in[10];
  const float* lnw = (const float*)d_in[11];
  const float* lnb = (const float*)d_in[12];

  char* ws = (char*)d_ws;
  const size_t NHB = (size_t)B_ * S_ * D_ * 2;
  const size_t NWB = (size_t)4 * D_ * D_ * 2;
  const size_t NQB = (size_t)B_ * H_ * S_ * DH_ * 2;
  u16* Hb = (u16*)ws;
  u16* Wb = (u16*)(ws + NHB);
  u16* Qb = (u16*)(ws + NHB + NWB);
  u16* Kb = (u16*)(ws + NHB + NWB + NQB);
  u16* Vt = (u16*)(ws + NHB + NWB + 2 * NQB);
  u16* Cb = (u16*)(ws + NHB + NWB + 3 * NQB);
  float* Of = (float*)(ws + NHB + NWB + 4 * NQB);
  u16* Vtmp = (u16*)Of;  // aliases Of; dead before mode-1 gemm writes Of

  cvt_kernel<<<2048, 256, 0, stream>>>(hid, qw, kw, vw, ow, Hb, Wb);

  gemm_kernel<<<dim3(18, 32), 256, 0, stream>>>(
      Hb, Wb, qb, kb, vb, Qb, Kb, Vtmp, nullptr, nullptr, 0);

  vtrans_kernel<<<dim3(S_ / 64, B_ * H_), 256, 0, stream>>>(Vtmp, Vt);

  attn_kernel<<<dim3(S_ / 64, H_, B_), 512, 0, stream>>>(Qb, Kb, Vt, bias, mask, Cb);

  gemm_kernel<<<dim3(6, 32), 256, 0, stream>>>(
      Cb, Wb + (size_t)3 * D_ * D_, nullptr, nullptr, nullptr,
      nullptr, nullptr, nullptr, Of, ob, 1);

  ln_kernel<<<B_ * S_, 192, 0, stream>>>(Of, hid, lnw, lnb, (float*)d_out);
}

// Round 10
// 161.058 us; speedup vs baseline: 2.1284x; 2.1284x over previous
//
#include <hip/hip_runtime.h>
#include <math.h>

typedef unsigned short u16;
typedef float f32x4 __attribute__((ext_vector_type(4)));
typedef __bf16 bf16x8 __attribute__((ext_vector_type(8)));

#define B_ 2
#define S_ 2048
#define D_ 768
#define H_ 12
#define DH_ 64

__device__ __forceinline__ u16 f2bf(float x) {
  union { float f; unsigned u; } v; v.f = x;
  unsigned r = v.u + 0x7fffu + ((v.u >> 16) & 1u);
  return (u16)(r >> 16);
}

__device__ __forceinline__ f32x4 zero4() { f32x4 z = {0.f, 0.f, 0.f, 0.f}; return z; }

__device__ __forceinline__ f32x4 mfma16(bf16x8 a, bf16x8 b, f32x4 c) {
  return __builtin_amdgcn_mfma_f32_16x16x32_bf16(a, b, c, 0, 0, 0);
}

__device__ __forceinline__ void gload_lds16(const void* g, void* l) {
  __builtin_amdgcn_global_load_lds((const __attribute__((address_space(1))) void*)g,
                                   (__attribute__((address_space(3))) void*)l, 16, 0, 0);
}

// ---------------- f32 -> bf16 conversion (hidden + 4 weights) ----------------
__global__ void cvt_kernel(const float* __restrict__ hid, const float* __restrict__ qw,
                           const float* __restrict__ kw, const float* __restrict__ vw,
                           const float* __restrict__ ow, u16* __restrict__ Hb,
                           u16* __restrict__ Wb) {
  const int NH = B_ * S_ * D_;      // 3145728
  const int NW = D_ * D_;           // 589824
  const int T4 = (NH + 4 * NW) >> 2;
  int stride = gridDim.x * blockDim.x;
  for (int i = blockIdx.x * blockDim.x + threadIdx.x; i < T4; i += stride) {
    int e = i << 2;
    const float* src; u16* dst;
    if (e < NH) { src = hid + e; dst = Hb + e; }
    else {
      int o = e - NH;
      int m = o / NW, oo = o - m * NW;
      src = (m == 0 ? qw : m == 1 ? kw : m == 2 ? vw : ow) + oo;
      dst = Wb + o;
    }
    f32x4 v = *(const f32x4*)src;
    uint2 o2;
    o2.x = (unsigned)f2bf(v[0]) | ((unsigned)f2bf(v[1]) << 16);
    o2.y = (unsigned)f2bf(v[2]) | ((unsigned)f2bf(v[3]) << 16);
    *(uint2*)dst = o2;
  }
}

// ---------------- GEMM: out = A @ W^T (+bias), m97 structure ----------------
#define BM 128
#define BN 128
#define BK 64

__global__ __launch_bounds__(256) void gemm_kernel(
    const u16* __restrict__ A, const u16* __restrict__ W,
    const float* __restrict__ bq, const float* __restrict__ bk, const float* __restrict__ bv,
    u16* __restrict__ Qb, u16* __restrict__ Kb, u16* __restrict__ Vtmp,
    float* __restrict__ Of, const float* __restrict__ bO, int mode)
{
  __shared__ __align__(16) u16 As[BM * BK];
  __shared__ __align__(16) u16 Bs[BN * BK];
  int t = threadIdx.x;
  int lane = t & 63, w = t >> 6;
  int wr = w >> 1, wc = w & 1;
  int l15 = lane & 15, l4 = lane >> 4;
  int m0 = blockIdx.y * BM, n0 = blockIdx.x * BN;

  f32x4 acc[4][4];
#pragma unroll
  for (int i = 0; i < 4; ++i)
#pragma unroll
    for (int j = 0; j < 4; ++j) acc[i][j] = zero4();

  const int K = D_;
  for (int k0 = 0; k0 < K; k0 += BK) {
    __syncthreads();
#pragma unroll
    for (int p = 0; p < 4; ++p) {
      int seg = p * 4 + w;
      int bd = seg * 64 + lane;
      int row = bd >> 3;
      int slot = (bd & 7) ^ (row & 7);
      gload_lds16(A + (size_t)(m0 + row) * K + k0 + slot * 8, (char*)As + seg * 1024);
      gload_lds16(W + (size_t)(n0 + row) * K + k0 + slot * 8, (char*)Bs + seg * 1024);
    }
    __syncthreads();
#pragma unroll
    for (int kk = 0; kk < 2; ++kk) {
      bf16x8 af[4], bfr[4];
#pragma unroll
      for (int i = 0; i < 4; ++i) {
        int ra = wr * 64 + i * 16 + l15;
        af[i] = *(const bf16x8*)((const char*)As + ra * 128 +
                                 ((kk * 64 + (l4 << 4)) ^ ((ra & 7) << 4)));
        int rb = wc * 64 + i * 16 + l15;
        bfr[i] = *(const bf16x8*)((const char*)Bs + rb * 128 +
                                  ((kk * 64 + (l4 << 4)) ^ ((rb & 7) << 4)));
      }
#pragma unroll
      for (int i = 0; i < 4; ++i)
#pragma unroll
        for (int j = 0; j < 4; ++j)
          acc[i][j] = mfma16(af[i], bfr[j], acc[i][j]);
    }
  }

  if (mode == 0) {
    int mat = n0 / D_;
    int ncol0 = (n0 - mat * D_) + wc * 64;
    const float* bias = (mat == 0) ? bq : (mat == 1 ? bk : bv);
    u16* outp = (mat == 0) ? Qb : (mat == 1 ? Kb : Vtmp);
    float scale = (mat == 0) ? 0.125f : 1.0f;
    int h = ncol0 >> 6;
#pragma unroll
    for (int j = 0; j < 4; ++j) {
      int d = j * 16 + l15;
      float bvv = bias[ncol0 + d];
#pragma unroll
      for (int i = 0; i < 4; ++i) {
#pragma unroll
        for (int r = 0; r < 4; ++r) {
          int m = m0 + wr * 64 + i * 16 + (l4 << 2) + r;
          int bb = m >> 11, ss = m & 2047;
          float val = (acc[i][j][r] + bvv) * scale;
          outp[(((size_t)bb * H_ + h) * S_ + ss) * DH_ + d] = f2bf(val);
        }
      }
    }
  } else {
#pragma unroll
    for (int j = 0; j < 4; ++j) {
      int n = n0 + wc * 64 + j * 16 + l15;
      float bvv = bO[n];
#pragma unroll
      for (int i = 0; i < 4; ++i) {
#pragma unroll
        for (int r = 0; r < 4; ++r) {
          int m = m0 + wr * 64 + i * 16 + (l4 << 2) + r;
          Of[(size_t)m * D_ + n] = acc[i][j][r] + bvv;
        }
      }
    }
  }
}

// ---------------- V transpose: [B,H,S,DH] -> [B,H,DH,S] ----------------
__global__ __launch_bounds__(256) void vtrans_kernel(const u16* __restrict__ V,
                                                     u16* __restrict__ Vt) {
  __shared__ __align__(16) u16 tile[64 * 64];
  int t = threadIdx.x;
  int s0 = blockIdx.x * 64;
  int bh = blockIdx.y;
  const u16* src = V + ((size_t)bh * S_ + s0) * DH_;
#pragma unroll
  for (int p = 0; p < 2; ++p) {
    int bd = t + p * 256;
    int row = bd >> 3, slot = bd & 7;
    uint4 v = *(const uint4*)(src + row * 64 + slot * 8);
    *(uint4*)((char*)tile + row * 128 + ((slot ^ (row & 7)) << 4)) = v;
  }
  __syncthreads();
  int d = t >> 2, sc = (t & 3) * 16;
  u16* dst = Vt + ((size_t)bh * DH_ + d) * S_ + s0 + sc;
  int colB = d * 2;
#pragma unroll
  for (int half = 0; half < 2; ++half) {
    u16 tmp[8] __attribute__((aligned(16)));
#pragma unroll
    for (int j = 0; j < 8; ++j) {
      int s = sc + half * 8 + j;
      tmp[j] = *(const u16*)((const char*)tile + s * 128 +
                             (((colB >> 4) ^ (s & 7)) << 4) + (colB & 15));
    }
    *(uint4*)(dst + half * 8) = *(const uint4*)tmp;
  }
}

// ---------------- flash attention: BATCH-MERGED blocks (bias fetched once) ----
// grid (64 qtiles, 12 h), 256 threads = 4 waves: wave w -> (b = w&1, qg = w>>1).
// Each wave computes 16 q-rows x 64 kv-cols for ITS batch; the 32x64 f32 bias
// tile is staged ONCE into LDS per iter (coalesced 1KB gload_lds bursts, XOR-
// swizzled) and shared by both batches -> bias L1-fill traffic halves. K/V for
// both batches staged per iter (L2-hot). Single-buffered, 2 barriers/iter.
// Fixed-reference softmax (scores bounded ~|8|); per-lane partial denominators;
// no cross-wave combine needed in epilogue.
__global__ __launch_bounds__(256, 3) void attn_kernel(
    const u16* __restrict__ Qb, const u16* __restrict__ Kb, const u16* __restrict__ Vt,
    const float* __restrict__ bias, const float* __restrict__ mask, u16* __restrict__ Cb)
{
  __shared__ __align__(16) u16 Ks[2][64 * 64];   // [batch][kv-row][dh]  16 KB
  __shared__ __align__(16) u16 Vs[2][64 * 64];   // [batch][d][kv]       16 KB
  __shared__ __align__(16) char Bls[8192];       // 32q x 64k f32, swizzled
  __shared__ __align__(16) u16 Ps[4][16][72];    // per-wave P scratch   9 KB

  int t = threadIdx.x, lane = t & 63, w = t >> 6;
  int b = w & 1, qg = w >> 1;
  int q0 = blockIdx.x * 32, h = blockIdx.y;
  int l15 = lane & 15, l4 = lane >> 4;

  const float* biasp = bias + ((size_t)h * S_ + q0) * S_;   // batch-independent
  const float* maskp = mask + (size_t)b * S_;
  size_t bh = (size_t)b * H_ + h;
  const u16* Qp = Qb + (bh * S_ + q0) * DH_;

  // staging geometry (per thread, two segments p=0,1; segment s = p*4+w)
  // K/V tiles: 64 rows x 128 B; row64 = s*8 + (lane>>3), slot = lane&7
  // bias tile: 32 rows x 256 B; row32 = s*4 + (lane>>4), 16B-chunk q16 = (lane&15)*16
  int r64_0 = (0 * 4 + w) * 8 + (lane >> 3), sl_0 = (lane & 7) ^ (r64_0 & 7);
  int r64_1 = (1 * 4 + w) * 8 + (lane >> 3), sl_1 = (lane & 7) ^ (r64_1 & 7);
  int r32_0 = (0 * 4 + w) * 4 + (lane >> 4);
  int r32_1 = (1 * 4 + w) * 4 + (lane >> 4);
  int q16 = (lane & 15) * 16;
  // source byte offsets pre-swizzled (rule #21: linear LDS dest + swizzled src)
  int bsw_0 = q16 ^ (((r32_0 >> 2) & 3) << 6);
  int bsw_1 = q16 ^ (((r32_1 >> 2) & 3) << 6);

  const u16* gK0[2], *gV0[2];
  const u16* gK1[2], *gV1[2];
#pragma unroll
  for (int b2 = 0; b2 < 2; ++b2) {
    size_t bh2 = (size_t)b2 * H_ + h;
    gK0[b2] = Kb + (bh2 * S_ + r64_0) * DH_ + sl_0 * 8;
    gK1[b2] = Kb + (bh2 * S_ + r64_1) * DH_ + sl_1 * 8;
    gV0[b2] = Vt + (bh2 * DH_ + r64_0) * S_ + sl_0 * 8;
    gV1[b2] = Vt + (bh2 * DH_ + r64_1) * S_ + sl_1 * 8;
  }
  const char* gB0 = (const char*)(biasp + (size_t)r32_0 * S_) + bsw_0;
  const char* gB1 = (const char*)(biasp + (size_t)r32_1 * S_) + bsw_1;

  // Q fragments (softmax scale pre-folded into Q)
  bf16x8 qf0, qf1;
  {
    const u16* qrow = Qp + (qg * 16 + l15) * DH_;
    qf0 = *(const bf16x8*)(qrow + l4 * 8);
    qf1 = *(const bf16x8*)(qrow + 32 + l4 * 8);
  }

  f32x4 oacc[4];
#pragma unroll
  for (int i = 0; i < 4; ++i) oacc[i] = zero4();
  float lrow[4] = {0.f, 0.f, 0.f, 0.f};

  for (int kt = 0; kt < S_ / 64; ++kt) {
    // ---- stage K/V (both batches) + shared bias tile ----
    {
      size_t ko = (size_t)kt * 64 * DH_;     // u16
      size_t vo = (size_t)kt * 64;           // u16
#pragma unroll
      for (int b2 = 0; b2 < 2; ++b2) {
        gload_lds16(gK0[b2] + ko, (char*)Ks[b2] + (0 * 4 + w) * 1024);
        gload_lds16(gK1[b2] + ko, (char*)Ks[b2] + (1 * 4 + w) * 1024);
        gload_lds16(gV0[b2] + vo, (char*)Vs[b2] + (0 * 4 + w) * 1024);
        gload_lds16(gV1[b2] + vo, (char*)Vs[b2] + (1 * 4 + w) * 1024);
      }
      gload_lds16(gB0 + (size_t)kt * 256, Bls + (0 * 4 + w) * 1024);
      gload_lds16(gB1 + (size_t)kt * 256, Bls + (1 * 4 + w) * 1024);
    }
    __syncthreads();   // stages visible (vmcnt drain)

    // ---- compute: this wave's batch, 16 q x 64 kv ----
    const u16* Kc = Ks[b];
    const u16* Vc = Vs[b];

    // S = Q K^T (scale pre-folded)
    f32x4 sf[4];
#pragma unroll
    for (int kf = 0; kf < 4; ++kf) {
      int row = kf * 16 + l15;
      bf16x8 kb0 = *(const bf16x8*)((const char*)Kc + row * 128 +
                                    ((l4 << 4) ^ ((row & 7) << 4)));
      bf16x8 kb1 = *(const bf16x8*)((const char*)Kc + row * 128 +
                                    ((64 + (l4 << 4)) ^ ((row & 7) << 4)));
      f32x4 s0 = zero4();
      s0 = mfma16(qf0, kb0, s0);
      s0 = mfma16(qf1, kb1, s0);
      sf[kf] = s0;
    }

    // p = exp(s + bias(LDS) + mask); per-lane partial denominators
#pragma unroll
    for (int kf = 0; kf < 4; ++kf) {
      float mk = maskp[kt * 64 + kf * 16 + l15];
      int col2 = (kf * 16 + l15) << 2;
#pragma unroll
      for (int r = 0; r < 4; ++r) {
        int row = qg * 16 + (l4 << 2) + r;
        float bv = *(const float*)(Bls + row * 256 +
                                   (col2 ^ (((row >> 2) & 3) << 6)));
        float p = __expf(sf[kf][r] + bv + mk);
        sf[kf][r] = p;
        lrow[r] += p;
      }
    }

    // P -> bf16 wave-local repack (C-layout -> A-fragment layout)
#pragma unroll
    for (int r = 0; r < 4; ++r)
#pragma unroll
      for (int kf = 0; kf < 4; ++kf)
        Ps[w][(l4 << 2) + r][kf * 16 + l15] = f2bf(sf[kf][r]);

    bf16x8 pa0 = *(const bf16x8*)&Ps[w][l15][l4 * 8];
    bf16x8 pa1 = *(const bf16x8*)&Ps[w][l15][32 + l4 * 8];

    // O += P V
#pragma unroll
    for (int df = 0; df < 4; ++df) {
      int row = df * 16 + l15;
      bf16x8 vb0 = *(const bf16x8*)((const char*)Vc + row * 128 +
                                    ((l4 << 4) ^ ((row & 7) << 4)));
      bf16x8 vb1 = *(const bf16x8*)((const char*)Vc + row * 128 +
                                    ((64 + (l4 << 4)) ^ ((row & 7) << 4)));
      oacc[df] = mfma16(pa0, vb0, oacc[df]);
      oacc[df] = mfma16(pa1, vb1, oacc[df]);
    }

    __syncthreads();   // all reads done before next stage overwrites
  }

  // ---- epilogue: reduce denominators over the 16-lane group, write bf16 ----
#pragma unroll
  for (int r = 0; r < 4; ++r) {
    float ls = lrow[r];
#pragma unroll
    for (int o = 1; o < 16; o <<= 1) ls += __shfl_xor(ls, o, 64);
    float inv = 1.0f / ls;
    int q = q0 + qg * 16 + (l4 << 2) + r;
    size_t base = ((size_t)b * S_ + q) * D_ + h * DH_ + l15;
#pragma unroll
    for (int df = 0; df < 4; ++df)
      Cb[base + df * 16] = f2bf(oacc[df][r] * inv);
  }
}

// ---------------- residual + LayerNorm ----------------
__global__ __launch_bounds__(192) void ln_kernel(const float* __restrict__ O,
                                                 const float* __restrict__ hid,
                                                 const float* __restrict__ lw,
                                                 const float* __restrict__ lb,
                                                 float* __restrict__ out) {
  int row = blockIdx.x, t = threadIdx.x;
  size_t base = (size_t)row * D_;
  f32x4 x = *(const f32x4*)(O + base + t * 4);
  f32x4 hh = *(const f32x4*)(hid + base + t * 4);
  x = x + hh;
  float s = x[0] + x[1] + x[2] + x[3];
  float s2 = x[0] * x[0] + x[1] * x[1] + x[2] * x[2] + x[3] * x[3];
#pragma unroll
  for (int o = 1; o < 64; o <<= 1) {
    s += __shfl_xor(s, o, 64);
    s2 += __shfl_xor(s2, o, 64);
  }
  __shared__ float rs[3], rs2[3];
  int w = t >> 6, lane = t & 63;
  if (lane == 0) { rs[w] = s; rs2[w] = s2; }
  __syncthreads();
  s = rs[0] + rs[1] + rs[2];
  s2 = rs2[0] + rs2[1] + rs2[2];
  float mu = s * (1.0f / 768.0f);
  float var = s2 * (1.0f / 768.0f) - mu * mu;
  float rstd = rsqrtf(var + 1e-12f);
  f32x4 w4 = *(const f32x4*)(lw + t * 4);
  f32x4 b4 = *(const f32x4*)(lb + t * 4);
  f32x4 y = (x - mu) * rstd * w4 + b4;
  *(f32x4*)(out + base + t * 4) = y;
}

// ---------------- launcher ----------------
extern "C" void kernel_launch(void* const* d_in, const int* in_sizes, int n_in,
                              void* d_out, int out_size, void* d_ws, size_t ws_size,
                              hipStream_t stream) {
  const float* hid  = (const float*)d_in[0];
  const float* mask = (const float*)d_in[1];
  const float* bias = (const float*)d_in[2];
  const float* qw = (const float*)d_in[3];
  const float* qb = (const float*)d_in[4];
  const float* kw = (const float*)d_in[5];
  const float* kb = (const float*)d_in[6];
  const float* vw = (const float*)d_in[7];
  const float* vb = (const float*)d_in[8];
  const float* ow = (const float*)d_in[9];
  const float* ob = (const float*)d_in[10];
  const float* lnw = (const float*)d_in[11];
  const float* lnb = (const float*)d_in[12];

  char* ws = (char*)d_ws;
  const size_t NHB = (size_t)B_ * S_ * D_ * 2;
  const size_t NWB = (size_t)4 * D_ * D_ * 2;
  const size_t NQB = (size_t)B_ * H_ * S_ * DH_ * 2;
  u16* Hb = (u16*)ws;
  u16* Wb = (u16*)(ws + NHB);
  u16* Qb = (u16*)(ws + NHB + NWB);
  u16* Kb = (u16*)(ws + NHB + NWB + NQB);
  u16* Vt = (u16*)(ws + NHB + NWB + 2 * NQB);
  u16* Cb = (u16*)(ws + NHB + NWB + 3 * NQB);
  float* Of = (float*)(ws + NHB + NWB + 4 * NQB);
  u16* Vtmp = (u16*)Of;  // aliases Of; dead before mode-1 gemm writes Of

  cvt_kernel<<<2048, 256, 0, stream>>>(hid, qw, kw, vw, ow, Hb, Wb);

  gemm_kernel<<<dim3(18, 32), 256, 0, stream>>>(
      Hb, Wb, qb, kb, vb, Qb, Kb, Vtmp, nullptr, nullptr, 0);

  vtrans_kernel<<<dim3(S_ / 64, B_ * H_), 256, 0, stream>>>(Vtmp, Vt);

  attn_kernel<<<dim3(64, 12), 256, 0, stream>>>(Qb, Kb, Vt, bias, mask, Cb);

  gemm_kernel<<<dim3(6, 32), 256, 0, stream>>>(
      Cb, Wb + (size_t)3 * D_ * D_, nullptr, nullptr, nullptr,
      nullptr, nullptr, nullptr, Of, ob, 1);

  ln_kernel<<<B_ * S_, 192, 0, stream>>>(Of, hid, lnw, lnb, (float*)d_out);
}

// Round 11
// 157.543 us; speedup vs baseline: 2.1758x; 1.0223x over previous
//
#include <hip/hip_runtime.h>
#include <math.h>

typedef unsigned short u16;
typedef float f32x4 __attribute__((ext_vector_type(4)));
typedef __bf16 bf16x8 __attribute__((ext_vector_type(8)));

#define B_ 2
#define S_ 2048
#define D_ 768
#define H_ 12
#define DH_ 64

__device__ __forceinline__ u16 f2bf(float x) {
  union { float f; unsigned u; } v; v.f = x;
  unsigned r = v.u + 0x7fffu + ((v.u >> 16) & 1u);
  return (u16)(r >> 16);
}

__device__ __forceinline__ f32x4 zero4() { f32x4 z = {0.f, 0.f, 0.f, 0.f}; return z; }

__device__ __forceinline__ f32x4 mfma16(bf16x8 a, bf16x8 b, f32x4 c) {
  return __builtin_amdgcn_mfma_f32_16x16x32_bf16(a, b, c, 0, 0, 0);
}

__device__ __forceinline__ void gload_lds16(const void* g, void* l) {
  __builtin_amdgcn_global_load_lds((const __attribute__((address_space(1))) void*)g,
                                   (__attribute__((address_space(3))) void*)l, 16, 0, 0);
}

// ---------------- f32 -> bf16 conversion (hidden + 4 weights) ----------------
__global__ void cvt_kernel(const float* __restrict__ hid, const float* __restrict__ qw,
                           const float* __restrict__ kw, const float* __restrict__ vw,
                           const float* __restrict__ ow, u16* __restrict__ Hb,
                           u16* __restrict__ Wb) {
  const int NH = B_ * S_ * D_;      // 3145728
  const int NW = D_ * D_;           // 589824
  const int T4 = (NH + 4 * NW) >> 2;
  int stride = gridDim.x * blockDim.x;
  for (int i = blockIdx.x * blockDim.x + threadIdx.x; i < T4; i += stride) {
    int e = i << 2;
    const float* src; u16* dst;
    if (e < NH) { src = hid + e; dst = Hb + e; }
    else {
      int o = e - NH;
      int m = o / NW, oo = o - m * NW;
      src = (m == 0 ? qw : m == 1 ? kw : m == 2 ? vw : ow) + oo;
      dst = Wb + o;
    }
    f32x4 v = *(const f32x4*)src;
    uint2 o2;
    o2.x = (unsigned)f2bf(v[0]) | ((unsigned)f2bf(v[1]) << 16);
    o2.y = (unsigned)f2bf(v[2]) | ((unsigned)f2bf(v[3]) << 16);
    *(uint2*)dst = o2;
  }
}

// ---------------- GEMM: out = A @ W^T (+bias), m97 structure ----------------
#define BM 128
#define BN 128
#define BK 64

__global__ __launch_bounds__(256) void gemm_kernel(
    const u16* __restrict__ A, const u16* __restrict__ W,
    const float* __restrict__ bq, const float* __restrict__ bk, const float* __restrict__ bv,
    u16* __restrict__ Qb, u16* __restrict__ Kb, u16* __restrict__ Vtmp,
    float* __restrict__ Of, const float* __restrict__ bO, int mode)
{
  __shared__ __align__(16) u16 As[BM * BK];
  __shared__ __align__(16) u16 Bs[BN * BK];
  int t = threadIdx.x;
  int lane = t & 63, w = t >> 6;
  int wr = w >> 1, wc = w & 1;
  int l15 = lane & 15, l4 = lane >> 4;
  int m0 = blockIdx.y * BM, n0 = blockIdx.x * BN;

  f32x4 acc[4][4];
#pragma unroll
  for (int i = 0; i < 4; ++i)
#pragma unroll
    for (int j = 0; j < 4; ++j) acc[i][j] = zero4();

  const int K = D_;
  for (int k0 = 0; k0 < K; k0 += BK) {
    __syncthreads();
#pragma unroll
    for (int p = 0; p < 4; ++p) {
      int seg = p * 4 + w;
      int bd = seg * 64 + lane;
      int row = bd >> 3;
      int slot = (bd & 7) ^ (row & 7);
      gload_lds16(A + (size_t)(m0 + row) * K + k0 + slot * 8, (char*)As + seg * 1024);
      gload_lds16(W + (size_t)(n0 + row) * K + k0 + slot * 8, (char*)Bs + seg * 1024);
    }
    __syncthreads();
#pragma unroll
    for (int kk = 0; kk < 2; ++kk) {
      bf16x8 af[4], bfr[4];
#pragma unroll
      for (int i = 0; i < 4; ++i) {
        int ra = wr * 64 + i * 16 + l15;
        af[i] = *(const bf16x8*)((const char*)As + ra * 128 +
                                 ((kk * 64 + (l4 << 4)) ^ ((ra & 7) << 4)));
        int rb = wc * 64 + i * 16 + l15;
        bfr[i] = *(const bf16x8*)((const char*)Bs + rb * 128 +
                                  ((kk * 64 + (l4 << 4)) ^ ((rb & 7) << 4)));
      }
#pragma unroll
      for (int i = 0; i < 4; ++i)
#pragma unroll
        for (int j = 0; j < 4; ++j)
          acc[i][j] = mfma16(af[i], bfr[j], acc[i][j]);
    }
  }

  if (mode == 0) {
    int mat = n0 / D_;
    int ncol0 = (n0 - mat * D_) + wc * 64;
    const float* bias = (mat == 0) ? bq : (mat == 1 ? bk : bv);
    u16* outp = (mat == 0) ? Qb : (mat == 1 ? Kb : Vtmp);
    float scale = (mat == 0) ? 0.125f : 1.0f;
    int h = ncol0 >> 6;
#pragma unroll
    for (int j = 0; j < 4; ++j) {
      int d = j * 16 + l15;
      float bvv = bias[ncol0 + d];
#pragma unroll
      for (int i = 0; i < 4; ++i) {
#pragma unroll
        for (int r = 0; r < 4; ++r) {
          int m = m0 + wr * 64 + i * 16 + (l4 << 2) + r;
          int bb = m >> 11, ss = m & 2047;
          float val = (acc[i][j][r] + bvv) * scale;
          outp[(((size_t)bb * H_ + h) * S_ + ss) * DH_ + d] = f2bf(val);
        }
      }
    }
  } else {
#pragma unroll
    for (int j = 0; j < 4; ++j) {
      int n = n0 + wc * 64 + j * 16 + l15;
      float bvv = bO[n];
#pragma unroll
      for (int i = 0; i < 4; ++i) {
#pragma unroll
        for (int r = 0; r < 4; ++r) {
          int m = m0 + wr * 64 + i * 16 + (l4 << 2) + r;
          Of[(size_t)m * D_ + n] = acc[i][j][r] + bvv;
        }
      }
    }
  }
}

// ---------------- V transpose: [B,H,S,DH] -> [B,H,DH,S] ----------------
__global__ __launch_bounds__(256) void vtrans_kernel(const u16* __restrict__ V,
                                                     u16* __restrict__ Vt) {
  __shared__ __align__(16) u16 tile[64 * 64];
  int t = threadIdx.x;
  int s0 = blockIdx.x * 64;
  int bh = blockIdx.y;
  const u16* src = V + ((size_t)bh * S_ + s0) * DH_;
#pragma unroll
  for (int p = 0; p < 2; ++p) {
    int bd = t + p * 256;
    int row = bd >> 3, slot = bd & 7;
    uint4 v = *(const uint4*)(src + row * 64 + slot * 8);
    *(uint4*)((char*)tile + row * 128 + ((slot ^ (row & 7)) << 4)) = v;
  }
  __syncthreads();
  int d = t >> 2, sc = (t & 3) * 16;
  u16* dst = Vt + ((size_t)bh * DH_ + d) * S_ + s0 + sc;
  int colB = d * 2;
#pragma unroll
  for (int half = 0; half < 2; ++half) {
    u16 tmp[8] __attribute__((aligned(16)));
#pragma unroll
    for (int j = 0; j < 8; ++j) {
      int s = sc + half * 8 + j;
      tmp[j] = *(const u16*)((const char*)tile + s * 128 +
                             (((colB >> 4) ^ (s & 7)) << 4) + (colB & 15));
    }
    *(uint4*)(dst + half * 8) = *(const uint4*)tmp;
  }
}

// ---------------- flash attention: reg-staged K/V + 2-deep prefetch ----
// grid (S/64, H, B), 512 threads = 8 waves; wave (qg=w&3, kg=w>>2) owns 16 q x
// 32 kv. K/V staged global->REG->ds_write (NO global_load_lds in the loop), so
// __syncthreads drains only lgkmcnt; bias/mask/KV global loads stay in flight
// across barriers and are waited (compiler-counted vmcnt) at USE, 2 tiles later.
// K-loop unrolled x2 with straight-line bodies and named register sets (no
// runtime set rotation -- the R9 scratch-spill fix). Fixed-reference softmax.
__global__ __launch_bounds__(512, 4) void attn_kernel(
    const u16* __restrict__ Qb, const u16* __restrict__ Kb, const u16* __restrict__ Vt,
    const float* __restrict__ bias, const float* __restrict__ mask, u16* __restrict__ Cb)
{
  __shared__ __align__(16) u16 Ks[2][64 * 64];
  __shared__ __align__(16) u16 Vs[2][64 * 64];
  // union: iter-phase Ps[4][16][72] u16 (9216 B) / epilogue Osh+Lsh (17408 B)
  __shared__ __align__(16) char upool[17408];
  u16 (*Ps)[16][72] = (u16 (*)[16][72])upool;
  float (*Osh)[16][66] = (float (*)[16][66])upool;
  float (*Lsh)[2][16] = (float (*)[2][16])(upool + 16896);

  int t = threadIdx.x, lane = t & 63, w = t >> 6;
  int qg = w & 3, kg = w >> 2;
  int q0 = blockIdx.x * 64, h = blockIdx.y, b = blockIdx.z;
  size_t bh = (size_t)b * H_ + h;
  const u16* Qp = Qb + (bh * S_ + q0) * DH_;
  const u16* Kp = Kb + bh * S_ * DH_;
  const u16* Vp = Vt + bh * DH_ * S_;             // [64][2048]
  const float* biasp = bias + ((size_t)h * S_ + q0) * S_;
  const float* maskp = mask + (size_t)b * S_;
  int l15 = lane & 15, l4 = lane >> 4;
  int kc0 = kg * 32;

  // bias row pointers (4 C-rows per thread), shifted to this wave's kv half
  const float* brp0 = biasp + (size_t)(qg * 16 + (l4 << 2) + 0) * S_ + kc0 + l15;
  const float* brp1 = brp0 + S_;
  const float* brp2 = brp1 + S_;
  const float* brp3 = brp2 + S_;
  const float* mkp = maskp + kc0 + l15;

  // reg-staging: thread handles row srow, 16B slot sslot; LDS dest swizzled
  int srow = t >> 3, sslot = t & 7;
  const u16* gK = Kp + (size_t)srow * DH_ + sslot * 8;   // + kt*4096 (u16)
  const u16* gV = Vp + (size_t)srow * S_ + sslot * 8;    // + kt*64   (u16)
  int lofs = srow * 128 + ((sslot ^ (srow & 7)) << 4);

  // Q fragments (softmax scale pre-folded)
  bf16x8 qf0, qf1;
  {
    const u16* qrow = Qp + (qg * 16 + l15) * DH_;
    qf0 = *(const bf16x8*)(qrow + l4 * 8);
    qf1 = *(const bf16x8*)(qrow + 32 + l4 * 8);
  }

  f32x4 oacc[4];
#pragma unroll
  for (int i = 0; i < 4; ++i) oacc[i] = zero4();
  float lrow[4] = {0.f, 0.f, 0.f, 0.f};

  // named 2-deep prefetch state
  uint4 stKe, stVe, stKo, stVo;           // K/V tiles: even-parity / odd-parity
  float bA0[2], bA1[2], bA2[2], bA3[2], mA[2];   // bias+mask, even tiles
  float bB0[2], bB1[2], bB2[2], bB3[2], mB[2];   // bias+mask, odd tiles

  // ---- prologue ----
  stKe = *(const uint4*)gK;                               // tile 0
  stVe = *(const uint4*)gV;
#pragma unroll
  for (int kf = 0; kf < 2; ++kf) {                        // bias tiles 0 (A), 1 (B)
    bA0[kf] = brp0[kf * 16];        bA1[kf] = brp1[kf * 16];
    bA2[kf] = brp2[kf * 16];        bA3[kf] = brp3[kf * 16];
    mA[kf]  = mkp[kf * 16];
    bB0[kf] = brp0[64 + kf * 16];   bB1[kf] = brp1[64 + kf * 16];
    bB2[kf] = brp2[64 + kf * 16];   bB3[kf] = brp3[64 + kf * 16];
    mB[kf]  = mkp[64 + kf * 16];
  }
  *(uint4*)((char*)Ks[0] + lofs) = stKe;                  // tile 0 -> buf0
  *(uint4*)((char*)Vs[0] + lofs) = stVe;
  stKo = *(const uint4*)(gK + 4096);                      // tile 1
  stVo = *(const uint4*)(gV + 64);
  stKe = *(const uint4*)(gK + 2 * 4096);                  // tile 2
  stVe = *(const uint4*)(gV + 2 * 64);
  __syncthreads();

  for (int kt = 0; kt < 32; kt += 2) {
    // ================= EVEN body: tile kt (buf0), bias set A =================
    // write tile kt+1 (odd regs) into buf1; issue loads for tile kt+3
    *(uint4*)((char*)Ks[1] + lofs) = stKo;
    *(uint4*)((char*)Vs[1] + lofs) = stVo;
    if (kt + 3 < 32) {
      stKo = *(const uint4*)(gK + (size_t)(kt + 3) * 4096);
      stVo = *(const uint4*)(gV + (size_t)(kt + 3) * 64);
    }
    {
      const u16* Kc = Ks[0];
      const u16* Vc = Vs[0];
      f32x4 sf[2];
#pragma unroll
      for (int kf = 0; kf < 2; ++kf) {
        int row = kc0 + kf * 16 + l15;
        bf16x8 kb0 = *(const bf16x8*)((const char*)Kc + row * 128 +
                                      ((l4 << 4) ^ ((row & 7) << 4)));
        bf16x8 kb1 = *(const bf16x8*)((const char*)Kc + row * 128 +
                                      ((64 + (l4 << 4)) ^ ((row & 7) << 4)));
        f32x4 s0 = zero4();
        s0 = mfma16(qf0, kb0, s0);
        s0 = mfma16(qf1, kb1, s0);
        sf[kf] = s0;
      }
#pragma unroll
      for (int kf = 0; kf < 2; ++kf) {
        float p0 = __expf(sf[kf][0] + bA0[kf] + mA[kf]);
        float p1 = __expf(sf[kf][1] + bA1[kf] + mA[kf]);
        float p2 = __expf(sf[kf][2] + bA2[kf] + mA[kf]);
        float p3 = __expf(sf[kf][3] + bA3[kf] + mA[kf]);
        sf[kf][0] = p0; sf[kf][1] = p1; sf[kf][2] = p2; sf[kf][3] = p3;
        lrow[0] += p0; lrow[1] += p1; lrow[2] += p2; lrow[3] += p3;
      }
      // reload set A for tile kt+2 (used 2 bodies later)
      if (kt + 2 < 32) {
        int kb2 = (kt + 2) * 64;
#pragma unroll
        for (int kf = 0; kf < 2; ++kf) {
          bA0[kf] = brp0[kb2 + kf * 16]; bA1[kf] = brp1[kb2 + kf * 16];
          bA2[kf] = brp2[kb2 + kf * 16]; bA3[kf] = brp3[kb2 + kf * 16];
          mA[kf]  = mkp[kb2 + kf * 16];
        }
      }
#pragma unroll
      for (int r = 0; r < 4; ++r)
#pragma unroll
        for (int kf = 0; kf < 2; ++kf)
          Ps[qg][(l4 << 2) + r][kc0 + kf * 16 + l15] = f2bf(sf[kf][r]);
      bf16x8 pa = *(const bf16x8*)&Ps[qg][l15][kc0 + l4 * 8];
#pragma unroll
      for (int df = 0; df < 4; ++df) {
        int row = df * 16 + l15;
        bf16x8 vb = *(const bf16x8*)((const char*)Vc + row * 128 +
                                     ((kg * 64 + (l4 << 4)) ^ ((row & 7) << 4)));
        oacc[df] = mfma16(pa, vb, oacc[df]);
      }
    }
    __syncthreads();

    // ================= ODD body: tile kt+1 (buf1), bias set B ================
    // write tile kt+2 (even regs) into buf0; issue loads for tile kt+4
    if (kt + 2 < 32) {
      *(uint4*)((char*)Ks[0] + lofs) = stKe;
      *(uint4*)((char*)Vs[0] + lofs) = stVe;
      if (kt + 4 < 32) {
        stKe = *(const uint4*)(gK + (size_t)(kt + 4) * 4096);
        stVe = *(const uint4*)(gV + (size_t)(kt + 4) * 64);
      }
    }
    {
      const u16* Kc = Ks[1];
      const u16* Vc = Vs[1];
      f32x4 sf[2];
#pragma unroll
      for (int kf = 0; kf < 2; ++kf) {
        int row = kc0 + kf * 16 + l15;
        bf16x8 kb0 = *(const bf16x8*)((const char*)Kc + row * 128 +
                                      ((l4 << 4) ^ ((row & 7) << 4)));
        bf16x8 kb1 = *(const bf16x8*)((const char*)Kc + row * 128 +
                                      ((64 + (l4 << 4)) ^ ((row & 7) << 4)));
        f32x4 s0 = zero4();
        s0 = mfma16(qf0, kb0, s0);
        s0 = mfma16(qf1, kb1, s0);
        sf[kf] = s0;
      }
#pragma unroll
      for (int kf = 0; kf < 2; ++kf) {
        float p0 = __expf(sf[kf][0] + bB0[kf] + mB[kf]);
        float p1 = __expf(sf[kf][1] + bB1[kf] + mB[kf]);
        float p2 = __expf(sf[kf][2] + bB2[kf] + mB[kf]);
        float p3 = __expf(sf[kf][3] + bB3[kf] + mB[kf]);
        sf[kf][0] = p0; sf[kf][1] = p1; sf[kf][2] = p2; sf[kf][3] = p3;
        lrow[0] += p0; lrow[1] += p1; lrow[2] += p2; lrow[3] += p3;
      }
      // reload set B for tile kt+3
      if (kt + 3 < 32) {
        int kb3 = (kt + 3) * 64;
#pragma unroll
        for (int kf = 0; kf < 2; ++kf) {
          bB0[kf] = brp0[kb3 + kf * 16]; bB1[kf] = brp1[kb3 + kf * 16];
          bB2[kf] = brp2[kb3 + kf * 16]; bB3[kf] = brp3[kb3 + kf * 16];
          mB[kf]  = mkp[kb3 + kf * 16];
        }
      }
#pragma unroll
      for (int r = 0; r < 4; ++r)
#pragma unroll
        for (int kf = 0; kf < 2; ++kf)
          Ps[qg][(l4 << 2) + r][kc0 + kf * 16 + l15] = f2bf(sf[kf][r]);
      bf16x8 pa = *(const bf16x8*)&Ps[qg][l15][kc0 + l4 * 8];
#pragma unroll
      for (int df = 0; df < 4; ++df) {
        int row = df * 16 + l15;
        bf16x8 vb = *(const bf16x8*)((const char*)Vc + row * 128 +
                                     ((kg * 64 + (l4 << 4)) ^ ((row & 7) << 4)));
        oacc[df] = mfma16(pa, vb, oacc[df]);
      }
    }
    __syncthreads();
  }

  // ---- epilogue: combine k-split partials, normalize, write bf16 ----
#pragma unroll
  for (int r = 0; r < 4; ++r) {
#pragma unroll
    for (int o = 1; o < 16; o <<= 1) lrow[r] += __shfl_xor(lrow[r], o, 64);
  }
  if (l15 == 0) {
#pragma unroll
    for (int r = 0; r < 4; ++r) Lsh[qg][kg][(l4 << 2) + r] = lrow[r];
  }
  if (kg == 1) {
#pragma unroll
    for (int r = 0; r < 4; ++r)
#pragma unroll
      for (int df = 0; df < 4; ++df)
        Osh[qg][(l4 << 2) + r][df * 16 + l15] = oacc[df][r];
  }
  __syncthreads();
  if (kg == 0) {
#pragma unroll
    for (int r = 0; r < 4; ++r) {
      int rr = (l4 << 2) + r;
      float inv = 1.0f / (Lsh[qg][0][rr] + Lsh[qg][1][rr]);
      int q = q0 + qg * 16 + rr;
      size_t base = ((size_t)b * S_ + q) * D_ + h * DH_ + l15;
#pragma unroll
      for (int df = 0; df < 4; ++df)
        Cb[base + df * 16] = f2bf((oacc[df][r] + Osh[qg][rr][df * 16 + l15]) * inv);
    }
  }
}

// ---------------- residual + LayerNorm ----------------
__global__ __launch_bounds__(192) void ln_kernel(const float* __restrict__ O,
                                                 const float* __restrict__ hid,
                                                 const float* __restrict__ lw,
                                                 const float* __restrict__ lb,
                                                 float* __restrict__ out) {
  int row = blockIdx.x, t = threadIdx.x;
  size_t base = (size_t)row * D_;
  f32x4 x = *(const f32x4*)(O + base + t * 4);
  f32x4 hh = *(const f32x4*)(hid + base + t * 4);
  x = x + hh;
  float s = x[0] + x[1] + x[2] + x[3];
  float s2 = x[0] * x[0] + x[1] * x[1] + x[2] * x[2] + x[3] * x[3];
#pragma unroll
  for (int o = 1; o < 64; o <<= 1) {
    s += __shfl_xor(s, o, 64);
    s2 += __shfl_xor(s2, o, 64);
  }
  __shared__ float rs[3], rs2[3];
  int w = t >> 6, lane = t & 63;
  if (lane == 0) { rs[w] = s; rs2[w] = s2; }
  __syncthreads();
  s = rs[0] + rs[1] + rs[2];
  s2 = rs2[0] + rs2[1] + rs2[2];
  float mu = s * (1.0f / 768.0f);
  float var = s2 * (1.0f / 768.0f) - mu * mu;
  float rstd = rsqrtf(var + 1e-12f);
  f32x4 w4 = *(const f32x4*)(lw + t * 4);
  f32x4 b4 = *(const f32x4*)(lb + t * 4);
  f32x4 y = (x - mu) * rstd * w4 + b4;
  *(f32x4*)(out + base + t * 4) = y;
}

// ---------------- launcher ----------------
extern "C" void kernel_launch(void* const* d_in, const int* in_sizes, int n_in,
                              void* d_out, int out_size, void* d_ws, size_t ws_size,
                              hipStream_t stream) {
  const float* hid  = (const float*)d_in[0];
  const float* mask = (const float*)d_in[1];
  const float* bias = (const float*)d_in[2];
  const float* qw = (const float*)d_in[3];
  const float* qb = (const float*)d_in[4];
  const float* kw = (const float*)d_in[5];
  const float* kb = (const float*)d_in[6];
  const float* vw = (const float*)d_in[7];
  const float* vb = (const float*)d_in[8];
  const float* ow = (const float*)d_in[9];
  const float* ob = (const float*)d_in[10];
  const float* lnw = (const float*)d_in[11];
  const float* lnb = (const float*)d_in[12];

  char* ws = (char*)d_ws;
  const size_t NHB = (size_t)B_ * S_ * D_ * 2;
  const size_t NWB = (size_t)4 * D_ * D_ * 2;
  const size_t NQB = (size_t)B_ * H_ * S_ * DH_ * 2;
  u16* Hb = (u16*)ws;
  u16* Wb = (u16*)(ws + NHB);
  u16* Qb = (u16*)(ws + NHB + NWB);
  u16* Kb = (u16*)(ws + NHB + NWB + NQB);
  u16* Vt = (u16*)(ws + NHB + NWB + 2 * NQB);
  u16* Cb = (u16*)(ws + NHB + NWB + 3 * NQB);
  float* Of = (float*)(ws + NHB + NWB + 4 * NQB);
  u16* Vtmp = (u16*)Of;  // aliases Of; dead before mode-1 gemm writes Of

  cvt_kernel<<<2048, 256, 0, stream>>>(hid, qw, kw, vw, ow, Hb, Wb);

  gemm_kernel<<<dim3(18, 32), 256, 0, stream>>>(
      Hb, Wb, qb, kb, vb, Qb, Kb, Vtmp, nullptr, nullptr, 0);

  vtrans_kernel<<<dim3(S_ / 64, B_ * H_), 256, 0, stream>>>(Vtmp, Vt);

  attn_kernel<<<dim3(S_ / 64, H_, B_), 512, 0, stream>>>(Qb, Kb, Vt, bias, mask, Cb);

  gemm_kernel<<<dim3(6, 32), 256, 0, stream>>>(
      Cb, Wb + (size_t)3 * D_ * D_, nullptr, nullptr, nullptr,
      nullptr, nullptr, nullptr, Of, ob, 1);

  ln_kernel<<<B_ * S_, 192, 0, stream>>>(Of, hid, lnw, lnb, (float*)d_out);
}